// Round 7
// baseline (519.780 us; speedup 1.0000x reference)
//
#include <hip/hip_runtime.h>
#include <cmath>

#define B_     8
#define T_     256
#define V_     32000
#define E_     512
#define OOV_   100
#define VE_    (V_ + OOV_)              // 32100
#define ROWS_  (B_ * T_)                // 2048
#define NV4_   (V_ / 4)                 // 8000 float4 per row
#define KFULL_ 31                       // 31 * 256 = 7936 float4
#define TAILT_ (NV4_ - KFULL_ * 256)    // 64 threads carry a 32nd float4
#define PAD4_  (OOV_ / 4)               // 25 float4 of zero padding
#define TOTAL_ ((size_t)ROWS_ * VE_)    // 65,740,800 floats

// One block of 256 threads per (b,t) row  →  8 independent blocks/CU
// (vs 2 with 1024-thread blocks): barrier convoys on one block are hidden
// by the other 7 streaming. __launch_bounds__(256,8) keeps 8 blocks/CU
// while allowing 64 VGPRs (2x the previous allocation) for deeper
// load pipelining. Pass 1 uses 4 independent online-(m,s) accumulators
// to break the loop-carried softmax dependency chain.
__global__ __launch_bounds__(256, 8) void pg_fused_kernel(
    const float* __restrict__ logits,
    const float* __restrict__ attn,   // (rows, 512)
    const float* __restrict__ ctx,    // (rows, 512)
    const float* __restrict__ hid,    // (rows, 1024)
    const float* __restrict__ dec,    // (rows, 512)
    const int*   __restrict__ enc,    // (B, 512)
    const float* __restrict__ pw,     // (2048,)
    const float* __restrict__ pb,     // (1,)
    float* __restrict__ out_total,    // (rows, 32100)
    float* __restrict__ out_pgen)     // (rows,)
{
  const int row  = blockIdx.x;
  const int tid  = threadIdx.x;
  const int lane = tid & 63;
  const int wid  = tid >> 6;          // 4 waves per block
  __shared__ float redA[4];
  __shared__ float redB[4];

  // -------- prefetch scatter operands (hide under everything) ----------
  const int b = row >> 8;             // T_ = 256
  const float av0 = attn[row * E_ + tid];
  const float av1 = attn[row * E_ + tid + 256];
  const int   ai0 = enc[b * E_ + tid];
  const int   ai1 = enc[b * E_ + tid + 256];

  // ---------------- pgen: dot(pre, w), 8 features/thread ----------------
  float acc = 0.f;
  #pragma unroll
  for (int k = 0; k < 8; ++k) {
    const int f = tid + (k << 8);
    float pv;
    if (f < 512)       pv = ctx[row * 512 + f];
    else if (f < 1536) pv = hid[row * 1024 + (f - 512)];
    else               pv = dec[row * 512 + (f - 1536)];
    acc += pv * pw[f];
  }
  #pragma unroll
  for (int o = 32; o > 0; o >>= 1) acc += __shfl_xor(acc, o);
  if (lane == 0) redA[wid] = acc;
  __syncthreads();
  float pgen;
  {
    // all threads read the 4 partials (broadcast from LDS) — no 2nd barrier
    const float dot = redA[0] + redA[1] + redA[2] + redA[3];
    pgen = 1.f / (1.f + __expf(-(dot + pb[0])));
  }
  __syncthreads();   // redA reused below

  // -------- pass 1: online (m,s), 4 independent accumulator lanes -------
  const float4* lrow = (const float4*)(logits + (size_t)row * V_);
  float mm[4] = {-3.0e38f, -3.0e38f, -3.0e38f, -3.0e38f};
  float ss[4] = {0.f, 0.f, 0.f, 0.f};
  #pragma unroll 8
  for (int k = 0; k < KFULL_; ++k) {
    const int j = k & 3;
    const float4 x = lrow[tid + (k << 8)];
    const float xm = fmaxf(fmaxf(x.x, x.y), fmaxf(x.z, x.w));
    const float nm = fmaxf(mm[j], xm);
    const float e0 = __expf(x.x - nm), e1 = __expf(x.y - nm);
    const float e2 = __expf(x.z - nm), e3 = __expf(x.w - nm);
    ss[j] = ss[j] * __expf(mm[j] - nm) + ((e0 + e1) + (e2 + e3));
    mm[j] = nm;
  }
  if (tid < TAILT_) {
    const float4 x = lrow[KFULL_ * 256 + tid];
    const float xm = fmaxf(fmaxf(x.x, x.y), fmaxf(x.z, x.w));
    const float nm = fmaxf(mm[0], xm);
    const float e0 = __expf(x.x - nm), e1 = __expf(x.y - nm);
    const float e2 = __expf(x.z - nm), e3 = __expf(x.w - nm);
    ss[0] = ss[0] * __expf(mm[0] - nm) + ((e0 + e1) + (e2 + e3));
    mm[0] = nm;
  }
  // merge the 4 accumulator lanes
  float m = fmaxf(fmaxf(mm[0], mm[1]), fmaxf(mm[2], mm[3]));
  float s = ss[0] * __expf(mm[0] - m) + ss[1] * __expf(mm[1] - m)
          + ss[2] * __expf(mm[2] - m) + ss[3] * __expf(mm[3] - m);

  // wave-level (m,s) merge
  #pragma unroll
  for (int o = 32; o > 0; o >>= 1) {
    const float om = __shfl_xor(m, o);
    const float os = __shfl_xor(s, o);
    const float nm = fmaxf(m, om);
    s = s * __expf(m - nm) + os * __expf(om - nm);
    m = nm;
  }
  if (lane == 0) { redA[wid] = m; redB[wid] = s; }
  __syncthreads();
  // all threads merge the 4 wave partials (broadcast reads, no barrier)
  float M = redA[0], S = redB[0];
  #pragma unroll
  for (int w = 1; w < 4; ++w) {
    const float om = redA[w], os = redB[w];
    const float nm = fmaxf(M, om);
    S = S * __expf(M - nm) + os * __expf(om - nm);
    M = nm;
  }
  const float scale = pgen / S;

  // -------- pass 2: re-read (L2-hot) row, write blended probs ----------
  float4* orow = (float4*)(out_total + (size_t)row * VE_);
  #pragma unroll 8
  for (int k = 0; k < KFULL_; ++k) {
    const int i = tid + (k << 8);
    const float4 x = lrow[i];
    float4 y;
    y.x = scale * __expf(x.x - M);
    y.y = scale * __expf(x.y - M);
    y.z = scale * __expf(x.z - M);
    y.w = scale * __expf(x.w - M);
    orow[i] = y;
  }
  if (tid < TAILT_) {
    const int i = KFULL_ * 256 + tid;
    const float4 x = lrow[i];
    float4 y;
    y.x = scale * __expf(x.x - M);
    y.y = scale * __expf(x.y - M);
    y.z = scale * __expf(x.z - M);
    y.w = scale * __expf(x.w - M);
    orow[i] = y;
  }
  if (tid < PAD4_) orow[NV4_ + tid] = make_float4(0.f, 0.f, 0.f, 0.f);
  if (tid == 0) out_pgen[row] = pgen;

  // ---------------- fused scatter into own (L2-hot) row ----------------
  __syncthreads();   // order plain stores (incl. pad) before atomics
  const float pc = 1.f - pgen;
  float* rbase = out_total + (size_t)row * VE_;
  unsafeAtomicAdd(rbase + ai0, pc * av0);
  unsafeAtomicAdd(rbase + ai1, pc * av1);
}

extern "C" void kernel_launch(void* const* d_in, const int* in_sizes, int n_in,
                              void* d_out, int out_size, void* d_ws, size_t ws_size,
                              hipStream_t stream) {
  const float* logits = (const float*)d_in[0];   // (8,256,32000)
  const float* attn   = (const float*)d_in[1];   // (8,256,512)
  const float* hid    = (const float*)d_in[2];   // (8,256,1024)
  const float* dec    = (const float*)d_in[3];   // (8,256,512)
  const float* ctx    = (const float*)d_in[4];   // (8,256,512)
  const int*   enc    = (const int*)d_in[5];     // (8,512)
  const float* pw     = (const float*)d_in[6];   // (1,2048)
  const float* pb     = (const float*)d_in[7];   // (1,)

  float* out_total = (float*)d_out;
  float* out_pgen  = out_total + TOTAL_;

  pg_fused_kernel<<<ROWS_, 256, 0, stream>>>(
      logits, attn, ctx, hid, dec, enc, pw, pb, out_total, out_pgen);
}